// Round 26
// baseline (209.227 us; speedup 1.0000x reference)
//
#include <hip/hip_runtime.h>
#include <cstdint>

typedef __attribute__((ext_vector_type(8))) __bf16 bf16x8;
typedef __attribute__((ext_vector_type(4))) float f32x4;

// ---------------- CSR build ----------------

__global__ __launch_bounds__(256) void k_hist(const int* __restrict__ ei,
        int E, int E2, int* __restrict__ deg) {
    int e = blockIdx.x * 256 + threadIdx.x;
    if (e >= E2) return;
    int dst = (e < E) ? ei[E + e] : (e - E);
    atomicAdd(&deg[dst], 1);
}

// per-2048-chunk sums
__global__ __launch_bounds__(256) void k_scanA(const int* __restrict__ deg,
        int* __restrict__ partials, int N) {
    int t = threadIdx.x;
    int base = blockIdx.x * 2048 + t * 8;
    int s = 0;
    #pragma unroll
    for (int j = 0; j < 8; ++j) { int i = base + j; if (i < N) s += deg[i]; }
    #pragma unroll
    for (int off = 32; off >= 1; off >>= 1) s += __shfl_xor(s, off, 64);
    __shared__ int ws[4];
    if ((t & 63) == 0) ws[t >> 6] = s;
    __syncthreads();
    if (t == 0) partials[blockIdx.x] = ws[0] + ws[1] + ws[2] + ws[3];
}

// block-local scan + inline prefix over raw partials (nb small)
__global__ __launch_bounds__(256) void k_scanC(const int* __restrict__ deg,
        const int* __restrict__ partials, int* __restrict__ row_start,
        int N, int nb) {
    int t = threadIdx.x;
    int bid = blockIdx.x;
    int boff = 0;
    for (int b = 0; b < bid; ++b) boff += partials[b];
    int base = bid * 2048 + t * 8;
    int v[8], s = 0;
    #pragma unroll
    for (int j = 0; j < 8; ++j) { int i = base + j; v[j] = (i < N) ? deg[i] : 0; s += v[j]; }
    int lane = t & 63, w = t >> 6;
    int incl = s;
    #pragma unroll
    for (int d = 1; d < 64; d <<= 1) {
        int u = __shfl_up(incl, d, 64);
        if (lane >= d) incl += u;
    }
    __shared__ int wsum[4];
    if (lane == 63) wsum[w] = incl;
    __syncthreads();
    int woff = 0;
    #pragma unroll
    for (int i = 0; i < 4; ++i) if (i < w) woff += wsum[i];
    int run = boff + woff + incl - s;
    #pragma unroll
    for (int j = 0; j < 8; ++j) {
        int i = base + j;
        if (i < N) row_start[i] = run;
        run += v[j];
    }
    if (bid == 0 && t == 0) {
        int tot = 0;
        for (int b = 0; b < nb; ++b) tot += partials[b];
        row_start[N] = tot;
    }
}

__global__ __launch_bounds__(256) void k_scatter(const int* __restrict__ ei,
        int E, int E2, const int* __restrict__ row_start, int* __restrict__ cursor,
        int* __restrict__ csr_src) {
    int e = blockIdx.x * 256 + threadIdx.x;
    if (e >= E2) return;
    int src, dst;
    if (e < E) { src = ei[e]; dst = ei[E + e]; }
    else       { src = e - E; dst = src; }
    int pos = row_start[dst] + atomicAdd(&cursor[dst], 1);
    csr_src[pos] = src;
}

// ---------------- W1/W2 -> fragment-linear bf16 (once) ----------------
// W1 (512x64): Wb1[((s*4+ct)*64+lane)*8+j], k=s*32+g*8+j, n=ct*16+(lane&15), g=lane>>4
// W2 (64x128): Wb2[((s*8+ct)*64+lane)*8+j], same k decomp (s in {0,1}), n=ct*16+(lane&15)

__global__ __launch_bounds__(256) void k_wconv(const float* __restrict__ W1,
        const float* __restrict__ W2, __bf16* __restrict__ Wb1,
        __bf16* __restrict__ Wb2) {
    int e = blockIdx.x * 256 + threadIdx.x;   // 32768 + 8192
    if (e < 32768) {
        int k = e >> 6, n = e & 63;
        int s = k >> 5, g = (k >> 3) & 3, j = k & 7;
        int ct = n >> 4;
        int lane = (n & 15) | (g << 4);
        Wb1[(((s * 4 + ct) * 64 + lane) << 3) + j] = (__bf16)W1[e];
    } else {
        int e2 = e - 32768;                   // 64x128
        int k = e2 >> 7, n = e2 & 127;
        int s = k >> 5, g = (k >> 3) & 3, j = k & 7;
        int ct = n >> 4;
        int lane = (n & 15) | (g << 4);
        Wb2[(((s * 8 + ct) * 64 + lane) << 3) + j] = (__bf16)W2[e2];
    }
}

// ---------------- GEMM1 (bf16 MFMA, K-split x2): bf16 partials h1pb ---------
// grid = 2 * ceil(N/64); half = bid&1 covers K range [half*256, half*256+256).
// Block = 4 waves = 64 rows. B-frags from 64KB L2-resident Wb1. Partials are
// stored bf16 (halves the round-trip traffic; fp32 sum happens in k_att1).

__global__ __launch_bounds__(256) void k_gemm1(const float* __restrict__ x,
        const __bf16* __restrict__ Wb, __bf16* __restrict__ h1pb, int N) {
    int bid = blockIdx.x;
    int half = bid & 1, tile = bid >> 1;
    int t = threadIdx.x;
    int l = t & 63, w = t >> 6;
    int g = l >> 4;
    int arow = tile * 64 + w * 16 + (l & 15);
    const float* xbase = x + (size_t)min(arow, N - 1) * 512 + g * 8;

    f32x4 acc[4] = {{0.f,0.f,0.f,0.f},{0.f,0.f,0.f,0.f},
                    {0.f,0.f,0.f,0.f},{0.f,0.f,0.f,0.f}};
    int s0 = half * 8;
    #pragma unroll 4
    for (int si = 0; si < 8; ++si) {
        int s = s0 + si;
        float4 xa = *(const float4*)(xbase + s * 32);
        float4 xb = *(const float4*)(xbase + s * 32 + 4);
        bf16x8 a;
        a[0] = (__bf16)xa.x; a[1] = (__bf16)xa.y; a[2] = (__bf16)xa.z; a[3] = (__bf16)xa.w;
        a[4] = (__bf16)xb.x; a[5] = (__bf16)xb.y; a[6] = (__bf16)xb.z; a[7] = (__bf16)xb.w;
        #pragma unroll
        for (int ct = 0; ct < 4; ++ct) {
            bf16x8 b = *reinterpret_cast<const bf16x8*>(Wb + (((s * 4 + ct) * 64 + l) << 3));
            acc[ct] = __builtin_amdgcn_mfma_f32_16x16x32_bf16(a, b, acc[ct], 0, 0, 0);
        }
    }
    __bf16* hp = h1pb + (size_t)half * N * 64;
    int orow0 = tile * 64 + w * 16 + g * 4;
    #pragma unroll
    for (int ct = 0; ct < 4; ++ct) {
        int col = ct * 16 + (l & 15);
        #pragma unroll
        for (int r = 0; r < 4; ++r) {
            int row = orow0 + r;
            if (row < N) hp[(size_t)row * 64 + col] = (__bf16)acc[ct][r];
        }
    }
}

// ---------------- combine halves + attention coeffs + h1b (bf16) ----------

__global__ __launch_bounds__(256) void k_att1(const __bf16* __restrict__ h1pb,
        const float* __restrict__ att_src, const float* __restrict__ att_dst,
        float* __restrict__ a_s, float* __restrict__ a_d,
        __bf16* __restrict__ h1b, int N) {
    int i = blockIdx.x * 256 + threadIdx.x;
    int NH = N * 8;
    if (i >= NH) return;
    int h = i & 7;
    bf16x8 A = *(const bf16x8*)(h1pb + (size_t)i * 8);
    bf16x8 B = *(const bf16x8*)(h1pb + (size_t)N * 64 + (size_t)i * 8);
    float v[8];
    #pragma unroll
    for (int c = 0; c < 8; ++c) v[c] = (float)A[c] + (float)B[c];
    const float* sp = att_src + h * 8;
    const float* dp = att_dst + h * 8;
    float s = 0.f, d = 0.f;
    bf16x8 hb;
    #pragma unroll
    for (int c = 0; c < 8; ++c) {
        s += v[c] * sp[c];
        d += v[c] * dp[c];
        hb[c] = (__bf16)v[c];
    }
    a_s[i] = s; a_d[i] = d;
    *(bf16x8*)(h1b + (size_t)i * 8) = hb;
}

// ---------------- GAT layer 1 (H=8, C=8) -> bf16 hmid_b (bias + ELU) --------

__global__ __launch_bounds__(256) void k_gat1(
        const int* __restrict__ row_start, const int* __restrict__ csr_src,
        const __bf16* __restrict__ h1b,
        const float* __restrict__ a_src, const float* __restrict__ a_dst,
        const float* __restrict__ bias, __bf16* __restrict__ outp, int N) {
    int node = blockIdx.x * 4 + (threadIdx.x >> 6);
    int lane = threadIdx.x & 63;
    if (node >= N) return;
    int j = lane >> 3, c = lane & 7;
    int start = row_start[node], end = row_start[node + 1];
    float adc = a_dst[(size_t)node * 8 + c];

    float acc[8] = {};
    float wsum = 0.f;
    #pragma unroll 2
    for (int base = start; base < end; base += 8) {
        int idx = base + j;
        if (idx < end) {
            int s = csr_src[idx];
            float a = a_src[(size_t)s * 8 + c] + adc;
            a = a > 0.f ? a : 0.2f * a;
            float w = __expf(a);
            wsum += w;
            bf16x8 v = *(const bf16x8*)(h1b + (size_t)s * 64 + c * 8);
            #pragma unroll
            for (int e = 0; e < 8; ++e) acc[e] = fmaf(w, (float)v[e], acc[e]);
        }
    }
    #pragma unroll
    for (int off = 8; off <= 32; off <<= 1) {
        wsum += __shfl_xor(wsum, off, 64);
        #pragma unroll
        for (int e = 0; e < 8; ++e) acc[e] += __shfl_xor(acc[e], off, 64);
    }
    if (j == 0) {
        float inv = 1.f / (wsum + 1e-16f);
        const float* bp = bias + c * 8;
        bf16x8 ob;
        #pragma unroll
        for (int e = 0; e < 8; ++e) {
            float v = acc[e] * inv + bp[e];
            v = v > 0.f ? v : __expf(v) - 1.f;  // ELU
            ob[e] = (__bf16)v;
        }
        *(bf16x8*)(outp + (size_t)node * 64 + c * 8) = ob;
    }
}

// ---------------- GEMM2 (bf16 MFMA) + fused att2: hmid_b @ Wb2 -> h2b, a2 ---

__global__ __launch_bounds__(256) void k_gemm2(const __bf16* __restrict__ hb,
        const __bf16* __restrict__ Wb, const float* __restrict__ att_src,
        const float* __restrict__ att_dst, __bf16* __restrict__ h2b,
        float* __restrict__ a2s, float* __restrict__ a2d, int N) {
    int t = threadIdx.x;
    int l = t & 63, w = t >> 6;
    int g = l >> 4;
    int arow = blockIdx.x * 64 + w * 16 + (l & 15);
    const __bf16* abase = hb + (size_t)min(arow, N - 1) * 64 + g * 8;

    bf16x8 a0 = *(const bf16x8*)(abase);
    bf16x8 a1 = *(const bf16x8*)(abase + 32);
    f32x4 acc[8];
    #pragma unroll
    for (int ct = 0; ct < 8; ++ct) acc[ct] = (f32x4){0.f,0.f,0.f,0.f};
    #pragma unroll
    for (int ct = 0; ct < 8; ++ct) {
        bf16x8 b0 = *reinterpret_cast<const bf16x8*>(Wb + ((ct * 64 + l) << 3));
        bf16x8 b1 = *reinterpret_cast<const bf16x8*>(Wb + (((8 + ct) * 64 + l) << 3));
        acc[ct] = __builtin_amdgcn_mfma_f32_16x16x32_bf16(a0, b0, acc[ct], 0, 0, 0);
        acc[ct] = __builtin_amdgcn_mfma_f32_16x16x32_bf16(a1, b1, acc[ct], 0, 0, 0);
    }
    int orow0 = blockIdx.x * 64 + w * 16 + g * 4;
    float sp[4] = {0.f,0.f,0.f,0.f}, dp[4] = {0.f,0.f,0.f,0.f};
    #pragma unroll
    for (int ct = 0; ct < 8; ++ct) {
        int col = ct * 16 + (l & 15);
        float as = att_src[col], ad = att_dst[col];
        #pragma unroll
        for (int r = 0; r < 4; ++r) {
            int row = orow0 + r;
            float v = acc[ct][r];
            if (row < N) h2b[(size_t)row * 128 + col] = (__bf16)v;
            sp[r] = fmaf(v, as, sp[r]);
            dp[r] = fmaf(v, ad, dp[r]);
        }
    }
    // reduce over the 16 lanes sharing (w,g) => full 128-col dot
    #pragma unroll
    for (int off = 1; off <= 8; off <<= 1) {
        #pragma unroll
        for (int r = 0; r < 4; ++r) {
            sp[r] += __shfl_xor(sp[r], off, 64);
            dp[r] += __shfl_xor(dp[r], off, 64);
        }
    }
    if ((l & 15) == 0) {
        #pragma unroll
        for (int r = 0; r < 4; ++r) {
            int row = orow0 + r;
            if (row < N) { a2s[row] = sp[r]; a2d[row] = dp[r]; }
        }
    }
}

// ---------------- GAT layer 2 (H=1, C=128), multi-edge lanes + bias ----------

__global__ __launch_bounds__(256) void k_gat2(
        const int* __restrict__ row_start, const int* __restrict__ csr_src,
        const __bf16* __restrict__ h2b,
        const float* __restrict__ a_src, const float* __restrict__ a_dst,
        const float* __restrict__ bias, float* __restrict__ outp, int N) {
    int node = blockIdx.x * 4 + (threadIdx.x >> 6);
    int lane = threadIdx.x & 63;
    if (node >= N) return;
    int j = lane >> 4, c = lane & 15;
    int start = row_start[node], end = row_start[node + 1];
    float adst = a_dst[node];

    float acc[8] = {};
    float wsum = 0.f;
    #pragma unroll 2
    for (int base = start; base < end; base += 4) {
        int idx = base + j;
        if (idx < end) {
            int s = csr_src[idx];
            float a = a_src[s] + adst;
            a = a > 0.f ? a : 0.2f * a;
            float w = __expf(a);
            wsum += w;
            bf16x8 v = *(const bf16x8*)(h2b + (size_t)s * 128 + c * 8);
            #pragma unroll
            for (int e = 0; e < 8; ++e) acc[e] = fmaf(w, (float)v[e], acc[e]);
        }
    }
    #pragma unroll
    for (int off = 16; off <= 32; off <<= 1) {
        wsum += __shfl_xor(wsum, off, 64);
        #pragma unroll
        for (int e = 0; e < 8; ++e) acc[e] += __shfl_xor(acc[e], off, 64);
    }
    if (j == 0) {
        float inv = 1.f / (wsum + 1e-16f);
        float* op = outp + (size_t)node * 128 + c * 8;
        const float* bp = bias + c * 8;
        #pragma unroll
        for (int e = 0; e < 8; ++e)
            op[e] = acc[e] * inv + bp[e];
    }
}

// ---------------- launcher ----------------

extern "C" void kernel_launch(void* const* d_in, const int* in_sizes, int n_in,
                              void* d_out, int out_size, void* d_ws, size_t ws_size,
                              hipStream_t stream) {
    const float* x   = (const float*)d_in[0];
    const int*   ei  = (const int*)d_in[1];     // integer inputs arrive as int32
    const float* W1  = (const float*)d_in[2];
    const float* as1 = (const float*)d_in[3];
    const float* ad1 = (const float*)d_in[4];
    const float* b1  = (const float*)d_in[5];
    const float* W2  = (const float*)d_in[6];
    const float* as2 = (const float*)d_in[7];
    const float* ad2 = (const float*)d_in[8];
    const float* b2  = (const float*)d_in[9];
    int N  = in_sizes[0] / 512;
    int E  = in_sizes[1] / 2;
    int E2 = E + N;

    char* wsp = (char*)d_ws;
    size_t off = 0;
    auto alloc = [&](size_t bytes) {
        char* p = wsp + off;
        off = (off + bytes + 255) & ~(size_t)255;
        return p;
    };
    __bf16* h1pb  = (__bf16*)alloc((size_t)2 * N * 64 * 2);  // bf16 K-split partials
    __bf16* h1b   = (__bf16*)alloc((size_t)N * 64 * 2);
    __bf16* hmidb = (__bf16*)alloc((size_t)N * 64 * 2);
    __bf16* h2b   = (__bf16*)alloc((size_t)N * 128 * 2);
    float*  a1s   = (float*)alloc((size_t)N * 8 * 4);
    float*  a1d   = (float*)alloc((size_t)N * 8 * 4);
    float*  a2s   = (float*)alloc((size_t)N * 4);
    float*  a2d   = (float*)alloc((size_t)N * 4);
    __bf16* Wb1   = (__bf16*)alloc((size_t)512 * 64 * 2);
    __bf16* Wb2   = (__bf16*)alloc((size_t)64 * 128 * 2);
    int* deg    = (int*)alloc((size_t)2 * N * 4);  // deg | cursor
    int* cursor = deg + N;
    int* row_start = (int*)alloc((size_t)(N + 1) * 4);
    int* csr_src   = (int*)alloc((size_t)E2 * 4);
    int nbscan = (N + 2047) / 2048;
    int* partials  = (int*)alloc((size_t)nbscan * 4);
    (void)ws_size; (void)n_in; (void)out_size;

    hipMemsetAsync(deg, 0, (size_t)2 * N * 4, stream);
    int eb = (E2 + 255) / 256;
    k_hist<<<eb, 256, 0, stream>>>(ei, E, E2, deg);
    k_scanA<<<nbscan, 256, 0, stream>>>(deg, partials, N);
    k_scanC<<<nbscan, 256, 0, stream>>>(deg, partials, row_start, N, nbscan);
    k_scatter<<<eb, 256, 0, stream>>>(ei, E, E2, row_start, cursor, csr_src);

    int gb64 = (N + 63) / 64;
    int nb4 = (N + 3) / 4;
    k_wconv<<<160, 256, 0, stream>>>(W1, W2, Wb1, Wb2);
    k_gemm1<<<gb64 * 2, 256, 0, stream>>>(x, Wb1, h1pb, N);
    k_att1<<<(N * 8 + 255) / 256, 256, 0, stream>>>(h1pb, as1, ad1, a1s, a1d, h1b, N);
    k_gat1<<<nb4, 256, 0, stream>>>(row_start, csr_src, h1b, a1s, a1d, b1, hmidb, N);
    k_gemm2<<<gb64, 256, 0, stream>>>(hmidb, Wb2, as2, ad2, h2b, a2s, a2d, N);
    k_gat2<<<nb4, 256, 0, stream>>>(row_start, csr_src, h2b, a2s, a2d, b2, (float*)d_out, N);
}

// Round 27
// 206.398 us; speedup vs baseline: 1.0137x; 1.0137x over previous
//
#include <hip/hip_runtime.h>
#include <cstdint>

typedef __attribute__((ext_vector_type(8))) __bf16 bf16x8;
typedef __attribute__((ext_vector_type(4))) float f32x4;

// ---------------- prep: zero deg/cursor + W1/W2 -> fragment-linear bf16 -----
// Independent elementwise ops merged into one dispatch (replaces
// hipMemsetAsync + k_wconv).

__global__ __launch_bounds__(256) void k_prep(const float* __restrict__ W1,
        const float* __restrict__ W2, __bf16* __restrict__ Wb1,
        __bf16* __restrict__ Wb2, int* __restrict__ deg, int N2) {
    int e = blockIdx.x * 256 + threadIdx.x;
    if (e < N2) deg[e] = 0;                   // deg | cursor
    if (e < 32768) {                          // W1: 512x64
        int k = e >> 6, n = e & 63;
        int s = k >> 5, g = (k >> 3) & 3, j = k & 7;
        int ct = n >> 4;
        int lane = (n & 15) | (g << 4);
        Wb1[(((s * 4 + ct) * 64 + lane) << 3) + j] = (__bf16)W1[e];
    } else if (e < 40960) {                   // W2: 64x128
        int e2 = e - 32768;
        int k = e2 >> 7, n = e2 & 127;
        int s = k >> 5, g = (k >> 3) & 3, j = k & 7;
        int ct = n >> 4;
        int lane = (n & 15) | (g << 4);
        Wb2[(((s * 8 + ct) * 64 + lane) << 3) + j] = (__bf16)W2[e2];
    }
}

// ---------------- CSR build ----------------

__global__ __launch_bounds__(256) void k_hist(const int* __restrict__ ei,
        int E, int E2, int* __restrict__ deg) {
    int e = blockIdx.x * 256 + threadIdx.x;
    if (e >= E2) return;
    int dst = (e < E) ? ei[E + e] : (e - E);
    atomicAdd(&deg[dst], 1);
}

// per-2048-chunk sums
__global__ __launch_bounds__(256) void k_scanA(const int* __restrict__ deg,
        int* __restrict__ partials, int N) {
    int t = threadIdx.x;
    int base = blockIdx.x * 2048 + t * 8;
    int s = 0;
    #pragma unroll
    for (int j = 0; j < 8; ++j) { int i = base + j; if (i < N) s += deg[i]; }
    #pragma unroll
    for (int off = 32; off >= 1; off >>= 1) s += __shfl_xor(s, off, 64);
    __shared__ int ws[4];
    if ((t & 63) == 0) ws[t >> 6] = s;
    __syncthreads();
    if (t == 0) partials[blockIdx.x] = ws[0] + ws[1] + ws[2] + ws[3];
}

// block-local scan + inline prefix over raw partials (nb small)
__global__ __launch_bounds__(256) void k_scanC(const int* __restrict__ deg,
        const int* __restrict__ partials, int* __restrict__ row_start,
        int N, int nb) {
    int t = threadIdx.x;
    int bid = blockIdx.x;
    int boff = 0;
    for (int b = 0; b < bid; ++b) boff += partials[b];
    int base = bid * 2048 + t * 8;
    int v[8], s = 0;
    #pragma unroll
    for (int j = 0; j < 8; ++j) { int i = base + j; v[j] = (i < N) ? deg[i] : 0; s += v[j]; }
    int lane = t & 63, w = t >> 6;
    int incl = s;
    #pragma unroll
    for (int d = 1; d < 64; d <<= 1) {
        int u = __shfl_up(incl, d, 64);
        if (lane >= d) incl += u;
    }
    __shared__ int wsum[4];
    if (lane == 63) wsum[w] = incl;
    __syncthreads();
    int woff = 0;
    #pragma unroll
    for (int i = 0; i < 4; ++i) if (i < w) woff += wsum[i];
    int run = boff + woff + incl - s;
    #pragma unroll
    for (int j = 0; j < 8; ++j) {
        int i = base + j;
        if (i < N) row_start[i] = run;
        run += v[j];
    }
    if (bid == 0 && t == 0) {
        int tot = 0;
        for (int b = 0; b < nb; ++b) tot += partials[b];
        row_start[N] = tot;
    }
}

__global__ __launch_bounds__(256) void k_scatter(const int* __restrict__ ei,
        int E, int E2, const int* __restrict__ row_start, int* __restrict__ cursor,
        int* __restrict__ csr_src) {
    int e = blockIdx.x * 256 + threadIdx.x;
    if (e >= E2) return;
    int src, dst;
    if (e < E) { src = ei[e]; dst = ei[E + e]; }
    else       { src = e - E; dst = src; }
    int pos = row_start[dst] + atomicAdd(&cursor[dst], 1);
    csr_src[pos] = src;
}

// ---------------- GEMM1 (bf16 MFMA, K-split x2): fp32 partials h1p ----------
// grid = 2 * ceil(N/64); half = bid&1 covers K range [half*256, half*256+256).
// Block = 4 waves = 64 rows. B-frags from 64KB L2-resident Wb1.

__global__ __launch_bounds__(256) void k_gemm1(const float* __restrict__ x,
        const __bf16* __restrict__ Wb, float* __restrict__ h1p, int N) {
    int bid = blockIdx.x;
    int half = bid & 1, tile = bid >> 1;
    int t = threadIdx.x;
    int l = t & 63, w = t >> 6;
    int g = l >> 4;
    int arow = tile * 64 + w * 16 + (l & 15);
    const float* xbase = x + (size_t)min(arow, N - 1) * 512 + g * 8;

    f32x4 acc[4] = {{0.f,0.f,0.f,0.f},{0.f,0.f,0.f,0.f},
                    {0.f,0.f,0.f,0.f},{0.f,0.f,0.f,0.f}};
    int s0 = half * 8;
    #pragma unroll 4
    for (int si = 0; si < 8; ++si) {
        int s = s0 + si;
        float4 xa = *(const float4*)(xbase + s * 32);
        float4 xb = *(const float4*)(xbase + s * 32 + 4);
        bf16x8 a;
        a[0] = (__bf16)xa.x; a[1] = (__bf16)xa.y; a[2] = (__bf16)xa.z; a[3] = (__bf16)xa.w;
        a[4] = (__bf16)xb.x; a[5] = (__bf16)xb.y; a[6] = (__bf16)xb.z; a[7] = (__bf16)xb.w;
        #pragma unroll
        for (int ct = 0; ct < 4; ++ct) {
            bf16x8 b = *reinterpret_cast<const bf16x8*>(Wb + (((s * 4 + ct) * 64 + l) << 3));
            acc[ct] = __builtin_amdgcn_mfma_f32_16x16x32_bf16(a, b, acc[ct], 0, 0, 0);
        }
    }
    float* hp = h1p + (size_t)half * N * 64;
    int orow0 = tile * 64 + w * 16 + g * 4;
    #pragma unroll
    for (int ct = 0; ct < 4; ++ct) {
        int col = ct * 16 + (l & 15);
        #pragma unroll
        for (int r = 0; r < 4; ++r) {
            int row = orow0 + r;
            if (row < N) hp[(size_t)row * 64 + col] = acc[ct][r];
        }
    }
}

// ---------------- combine halves + attention coeffs + h1b (bf16) ----------

__global__ __launch_bounds__(256) void k_att1(const float* __restrict__ h1p,
        const float* __restrict__ att_src, const float* __restrict__ att_dst,
        float* __restrict__ a_s, float* __restrict__ a_d,
        __bf16* __restrict__ h1b, int N) {
    int i = blockIdx.x * 256 + threadIdx.x;
    int NH = N * 8;
    if (i >= NH) return;
    int h = i & 7;
    const float* p0 = h1p + (size_t)i * 8;
    const float* p1 = h1p + (size_t)N * 64 + (size_t)i * 8;
    float4 a0 = *(const float4*)p0,       a1 = *(const float4*)(p0 + 4);
    float4 b0 = *(const float4*)p1,       b1 = *(const float4*)(p1 + 4);
    float v[8] = { a0.x + b0.x, a0.y + b0.y, a0.z + b0.z, a0.w + b0.w,
                   a1.x + b1.x, a1.y + b1.y, a1.z + b1.z, a1.w + b1.w };
    const float* sp = att_src + h * 8;
    const float* dp = att_dst + h * 8;
    float s = 0.f, d = 0.f;
    bf16x8 hb;
    #pragma unroll
    for (int c = 0; c < 8; ++c) {
        s += v[c] * sp[c];
        d += v[c] * dp[c];
        hb[c] = (__bf16)v[c];
    }
    a_s[i] = s; a_d[i] = d;
    *(bf16x8*)(h1b + (size_t)i * 8) = hb;
}

// ---------------- GAT layer 1 (H=8, C=8) -> bf16 hmid_b (bias + ELU) --------

__global__ __launch_bounds__(256) void k_gat1(
        const int* __restrict__ row_start, const int* __restrict__ csr_src,
        const __bf16* __restrict__ h1b,
        const float* __restrict__ a_src, const float* __restrict__ a_dst,
        const float* __restrict__ bias, __bf16* __restrict__ outp, int N) {
    int node = blockIdx.x * 4 + (threadIdx.x >> 6);
    int lane = threadIdx.x & 63;
    if (node >= N) return;
    int j = lane >> 3, c = lane & 7;
    int start = row_start[node], end = row_start[node + 1];
    float adc = a_dst[(size_t)node * 8 + c];

    float acc[8] = {};
    float wsum = 0.f;
    #pragma unroll 2
    for (int base = start; base < end; base += 8) {
        int idx = base + j;
        if (idx < end) {
            int s = csr_src[idx];
            float a = a_src[(size_t)s * 8 + c] + adc;
            a = a > 0.f ? a : 0.2f * a;
            float w = __expf(a);
            wsum += w;
            bf16x8 v = *(const bf16x8*)(h1b + (size_t)s * 64 + c * 8);
            #pragma unroll
            for (int e = 0; e < 8; ++e) acc[e] = fmaf(w, (float)v[e], acc[e]);
        }
    }
    #pragma unroll
    for (int off = 8; off <= 32; off <<= 1) {
        wsum += __shfl_xor(wsum, off, 64);
        #pragma unroll
        for (int e = 0; e < 8; ++e) acc[e] += __shfl_xor(acc[e], off, 64);
    }
    if (j == 0) {
        float inv = 1.f / (wsum + 1e-16f);
        const float* bp = bias + c * 8;
        bf16x8 ob;
        #pragma unroll
        for (int e = 0; e < 8; ++e) {
            float v = acc[e] * inv + bp[e];
            v = v > 0.f ? v : __expf(v) - 1.f;  // ELU
            ob[e] = (__bf16)v;
        }
        *(bf16x8*)(outp + (size_t)node * 64 + c * 8) = ob;
    }
}

// ---------------- GEMM2 (bf16 MFMA) + fused att2: hmid_b @ Wb2 -> h2b, a2 ---

__global__ __launch_bounds__(256) void k_gemm2(const __bf16* __restrict__ hb,
        const __bf16* __restrict__ Wb, const float* __restrict__ att_src,
        const float* __restrict__ att_dst, __bf16* __restrict__ h2b,
        float* __restrict__ a2s, float* __restrict__ a2d, int N) {
    int t = threadIdx.x;
    int l = t & 63, w = t >> 6;
    int g = l >> 4;
    int arow = blockIdx.x * 64 + w * 16 + (l & 15);
    const __bf16* abase = hb + (size_t)min(arow, N - 1) * 64 + g * 8;

    bf16x8 a0 = *(const bf16x8*)(abase);
    bf16x8 a1 = *(const bf16x8*)(abase + 32);
    f32x4 acc[8];
    #pragma unroll
    for (int ct = 0; ct < 8; ++ct) acc[ct] = (f32x4){0.f,0.f,0.f,0.f};
    #pragma unroll
    for (int ct = 0; ct < 8; ++ct) {
        bf16x8 b0 = *reinterpret_cast<const bf16x8*>(Wb + ((ct * 64 + l) << 3));
        bf16x8 b1 = *reinterpret_cast<const bf16x8*>(Wb + (((8 + ct) * 64 + l) << 3));
        acc[ct] = __builtin_amdgcn_mfma_f32_16x16x32_bf16(a0, b0, acc[ct], 0, 0, 0);
        acc[ct] = __builtin_amdgcn_mfma_f32_16x16x32_bf16(a1, b1, acc[ct], 0, 0, 0);
    }
    int orow0 = blockIdx.x * 64 + w * 16 + g * 4;
    float sp[4] = {0.f,0.f,0.f,0.f}, dp[4] = {0.f,0.f,0.f,0.f};
    #pragma unroll
    for (int ct = 0; ct < 8; ++ct) {
        int col = ct * 16 + (l & 15);
        float as = att_src[col], ad = att_dst[col];
        #pragma unroll
        for (int r = 0; r < 4; ++r) {
            int row = orow0 + r;
            float v = acc[ct][r];
            if (row < N) h2b[(size_t)row * 128 + col] = (__bf16)v;
            sp[r] = fmaf(v, as, sp[r]);
            dp[r] = fmaf(v, ad, dp[r]);
        }
    }
    // reduce over the 16 lanes sharing (w,g) => full 128-col dot
    #pragma unroll
    for (int off = 1; off <= 8; off <<= 1) {
        #pragma unroll
        for (int r = 0; r < 4; ++r) {
            sp[r] += __shfl_xor(sp[r], off, 64);
            dp[r] += __shfl_xor(dp[r], off, 64);
        }
    }
    if ((l & 15) == 0) {
        #pragma unroll
        for (int r = 0; r < 4; ++r) {
            int row = orow0 + r;
            if (row < N) { a2s[row] = sp[r]; a2d[row] = dp[r]; }
        }
    }
}

// ---------------- GAT layer 2 (H=1, C=128), multi-edge lanes + bias ----------

__global__ __launch_bounds__(256) void k_gat2(
        const int* __restrict__ row_start, const int* __restrict__ csr_src,
        const __bf16* __restrict__ h2b,
        const float* __restrict__ a_src, const float* __restrict__ a_dst,
        const float* __restrict__ bias, float* __restrict__ outp, int N) {
    int node = blockIdx.x * 4 + (threadIdx.x >> 6);
    int lane = threadIdx.x & 63;
    if (node >= N) return;
    int j = lane >> 4, c = lane & 15;
    int start = row_start[node], end = row_start[node + 1];
    float adst = a_dst[node];

    float acc[8] = {};
    float wsum = 0.f;
    #pragma unroll 2
    for (int base = start; base < end; base += 4) {
        int idx = base + j;
        if (idx < end) {
            int s = csr_src[idx];
            float a = a_src[s] + adst;
            a = a > 0.f ? a : 0.2f * a;
            float w = __expf(a);
            wsum += w;
            bf16x8 v = *(const bf16x8*)(h2b + (size_t)s * 128 + c * 8);
            #pragma unroll
            for (int e = 0; e < 8; ++e) acc[e] = fmaf(w, (float)v[e], acc[e]);
        }
    }
    #pragma unroll
    for (int off = 16; off <= 32; off <<= 1) {
        wsum += __shfl_xor(wsum, off, 64);
        #pragma unroll
        for (int e = 0; e < 8; ++e) acc[e] += __shfl_xor(acc[e], off, 64);
    }
    if (j == 0) {
        float inv = 1.f / (wsum + 1e-16f);
        float* op = outp + (size_t)node * 128 + c * 8;
        const float* bp = bias + c * 8;
        #pragma unroll
        for (int e = 0; e < 8; ++e)
            op[e] = acc[e] * inv + bp[e];
    }
}

// ---------------- launcher ----------------

extern "C" void kernel_launch(void* const* d_in, const int* in_sizes, int n_in,
                              void* d_out, int out_size, void* d_ws, size_t ws_size,
                              hipStream_t stream) {
    const float* x   = (const float*)d_in[0];
    const int*   ei  = (const int*)d_in[1];     // integer inputs arrive as int32
    const float* W1  = (const float*)d_in[2];
    const float* as1 = (const float*)d_in[3];
    const float* ad1 = (const float*)d_in[4];
    const float* b1  = (const float*)d_in[5];
    const float* W2  = (const float*)d_in[6];
    const float* as2 = (const float*)d_in[7];
    const float* ad2 = (const float*)d_in[8];
    const float* b2  = (const float*)d_in[9];
    int N  = in_sizes[0] / 512;
    int E  = in_sizes[1] / 2;
    int E2 = E + N;

    char* wsp = (char*)d_ws;
    size_t off = 0;
    auto alloc = [&](size_t bytes) {
        char* p = wsp + off;
        off = (off + bytes + 255) & ~(size_t)255;
        return p;
    };
    float*  h1p   = (float*)alloc((size_t)2 * N * 64 * 4);   // K-split partials
    __bf16* h1b   = (__bf16*)alloc((size_t)N * 64 * 2);
    __bf16* hmidb = (__bf16*)alloc((size_t)N * 64 * 2);
    __bf16* h2b   = (__bf16*)alloc((size_t)N * 128 * 2);
    float*  a1s   = (float*)alloc((size_t)N * 8 * 4);
    float*  a1d   = (float*)alloc((size_t)N * 8 * 4);
    float*  a2s   = (float*)alloc((size_t)N * 4);
    float*  a2d   = (float*)alloc((size_t)N * 4);
    __bf16* Wb1   = (__bf16*)alloc((size_t)512 * 64 * 2);
    __bf16* Wb2   = (__bf16*)alloc((size_t)64 * 128 * 2);
    int* deg    = (int*)alloc((size_t)2 * N * 4);  // deg | cursor
    int* cursor = deg + N;
    int* row_start = (int*)alloc((size_t)(N + 1) * 4);
    int* csr_src   = (int*)alloc((size_t)E2 * 4);
    int nbscan = (N + 2047) / 2048;
    int* partials  = (int*)alloc((size_t)nbscan * 4);
    (void)ws_size; (void)n_in; (void)out_size;

    int eb = (E2 + 255) / 256;
    int prep_n = 2 * N > 40960 ? 2 * N : 40960;
    k_prep<<<(prep_n + 255) / 256, 256, 0, stream>>>(W1, W2, Wb1, Wb2, deg, 2 * N);
    k_hist<<<eb, 256, 0, stream>>>(ei, E, E2, deg);
    k_scanA<<<nbscan, 256, 0, stream>>>(deg, partials, N);
    k_scanC<<<nbscan, 256, 0, stream>>>(deg, partials, row_start, N, nbscan);
    k_scatter<<<eb, 256, 0, stream>>>(ei, E, E2, row_start, cursor, csr_src);

    int gb64 = (N + 63) / 64;
    int nb4 = (N + 3) / 4;
    k_gemm1<<<gb64 * 2, 256, 0, stream>>>(x, Wb1, h1p, N);
    k_att1<<<(N * 8 + 255) / 256, 256, 0, stream>>>(h1p, as1, ad1, a1s, a1d, h1b, N);
    k_gat1<<<nb4, 256, 0, stream>>>(row_start, csr_src, h1b, a1s, a1d, b1, hmidb, N);
    k_gemm2<<<gb64, 256, 0, stream>>>(hmidb, Wb2, as2, ad2, h2b, a2s, a2d, N);
    k_gat2<<<nb4, 256, 0, stream>>>(row_start, csr_src, h2b, a2s, a2d, b2, (float*)d_out, N);
}